// Round 3
// baseline (7948.972 us; speedup 1.0000x reference)
//
#include <hip/hip_runtime.h>
#include <math.h>

#define NN 65536
#define TWO_N (2 * NN)
#define VOCAB 1000
#define MD 256
#define G3 768
#define DMAX 65536
#define NB 16
#define NT 256
#define DFIX 48

struct Params {
    const int* l_tokens; const int* l_parent;
    const int* r_tokens; const int* r_parent;
    const float* emb_W;
    const float* Wioux; const float* bioux;
    const float* Wiouh; const float* biouh;
    const float* Wfx;   const float* bfx;
    const float* Wfh;   const float* bfh;
    const float* Wh;    const float* bh;
    const float* Wp;    const float* bp;
    float* out;
    // workspace
    float* E_ioux;   // [VOCAB][768]  (includes bioux)
    float* E_fx;     // [VOCAB][256]  (includes bfx)
    float* h_sum;    // [NN][256]  (one tree at a time)
    float* fc_sum;   // [NN][256]
    float* c_root;   // [2][256]
    int* anc_a; int* anc_b; int* dep_a; int* dep_b;  // [2N]
    int* cnt; int* offs; int* cur;                    // [2*DMAX] (tree-major)
    int* order;                                        // [2N] (tree 0 nodes first)
    int* maxd;                                         // [2]
};

union SMem {
    struct { float es[4][MD]; } e;
    struct {
        float hls[NB][MD];
        int nid[NB]; int loc[NB]; int tok[NB]; int par[NB]; int ptok[NB];
    } w;
    struct { float vec[2 * MD]; float red[2][NT]; } h;
};

__device__ __forceinline__ float sigmoidf_(float x) {
    return 1.0f / (1.0f + __expf(-x));
}
__device__ __forceinline__ float tanhf_(float x) {
    float ex = __expf(2.0f * x);
    return 1.0f - 2.0f / (ex + 1.0f);
}

// processes NB nodes of ONE tree; state arrays are local-indexed [NN][256]
__device__ void process_group(const Params& P, SMem& sm, int base, int cntv,
                              int t, bool fence) {
    __syncthreads();   // protect smem reuse from previous group
    if (t < NB) {
        int g = -1, loc = 0, tok = 0, par = 0, ptok = 0;
        if (t < cntv) {
            g = P.order[base + t];
            int tree = g >> 16, i = g & (NN - 1);
            const int* toks = tree ? P.r_tokens : P.l_tokens;
            const int* pars = tree ? P.r_parent : P.l_parent;
            loc = i;
            tok = toks[i];
            int pl = pars[i];
            par = pl;
            ptok = toks[pl];
        }
        sm.w.nid[t] = g; sm.w.loc[t] = loc; sm.w.tok[t] = tok;
        sm.w.par[t] = par; sm.w.ptok[t] = ptok;
    }
    __syncthreads();
    #pragma unroll
    for (int nb = 0; nb < NB; ++nb) {
        int g = sm.w.nid[nb];
        sm.w.hls[nb][t] = (g >= 0) ? P.h_sum[(size_t)sm.w.loc[nb] * MD + t] : 0.0f;
    }
    __syncthreads();

    // ---- iou = E_ioux[tok] + h_sum @ Wiouh + biouh ; thread t owns element t ----
    float ai[NB], ao[NB], au[NB];
    #pragma unroll
    for (int nb = 0; nb < NB; ++nb) { ai[nb] = 0.f; ao[nb] = 0.f; au[nb] = 0.f; }
    const float* W = P.Wiouh;
    for (int k = 0; k < MD; k += 4) {
        float wi0 = W[(k + 0) * G3 + t];
        float wi1 = W[(k + 1) * G3 + t];
        float wi2 = W[(k + 2) * G3 + t];
        float wi3 = W[(k + 3) * G3 + t];
        float wo0 = W[(k + 0) * G3 + 256 + t];
        float wo1 = W[(k + 1) * G3 + 256 + t];
        float wo2 = W[(k + 2) * G3 + 256 + t];
        float wo3 = W[(k + 3) * G3 + 256 + t];
        float wu0 = W[(k + 0) * G3 + 512 + t];
        float wu1 = W[(k + 1) * G3 + 512 + t];
        float wu2 = W[(k + 2) * G3 + 512 + t];
        float wu3 = W[(k + 3) * G3 + 512 + t];
        #pragma unroll
        for (int nb = 0; nb < NB; ++nb) {
            float4 hv = *(const float4*)&sm.w.hls[nb][k];
            ai[nb] += wi0 * hv.x; ai[nb] += wi1 * hv.y; ai[nb] += wi2 * hv.z; ai[nb] += wi3 * hv.w;
            ao[nb] += wo0 * hv.x; ao[nb] += wo1 * hv.y; ao[nb] += wo2 * hv.z; ao[nb] += wo3 * hv.w;
            au[nb] += wu0 * hv.x; au[nb] += wu1 * hv.y; au[nb] += wu2 * hv.z; au[nb] += wu3 * hv.w;
        }
    }

    // ---- gates, c, h ----
    float cv[NB];
    float b_i = P.biouh[t], b_o = P.biouh[256 + t], b_u = P.biouh[512 + t];
    __syncthreads();   // all threads done reading h_sum rows in hls
    #pragma unroll
    for (int nb = 0; nb < NB; ++nb) {
        int g = sm.w.nid[nb];
        float hval = 0.0f, cval = 0.0f;
        if (g >= 0) {
            const float* Ei = P.E_ioux + (size_t)sm.w.tok[nb] * G3;
            float ig = Ei[t] + ai[nb] + b_i;
            float og = Ei[256 + t] + ao[nb] + b_o;
            float ug = Ei[512 + t] + au[nb] + b_u;
            cval = sigmoidf_(ig) * tanhf_(ug) + P.fc_sum[(size_t)sm.w.loc[nb] * MD + t];
            hval = sigmoidf_(og) * tanhf_(cval);
        }
        cv[nb] = cval;
        sm.w.hls[nb][t] = hval;   // overwrite with h
    }
    __syncthreads();

    // ---- f = sigmoid(h @ Wfh + bfh + E_fx[ptok]) ; scatter to parent ----
    float af[NB];
    #pragma unroll
    for (int nb = 0; nb < NB; ++nb) af[nb] = 0.f;
    const float* Wf = P.Wfh;
    for (int k = 0; k < MD; k += 4) {
        float wf0 = Wf[(k + 0) * MD + t];
        float wf1 = Wf[(k + 1) * MD + t];
        float wf2 = Wf[(k + 2) * MD + t];
        float wf3 = Wf[(k + 3) * MD + t];
        #pragma unroll
        for (int nb = 0; nb < NB; ++nb) {
            float4 hv = *(const float4*)&sm.w.hls[nb][k];
            af[nb] += wf0 * hv.x; af[nb] += wf1 * hv.y; af[nb] += wf2 * hv.z; af[nb] += wf3 * hv.w;
        }
    }
    float b_f = P.bfh[t];
    #pragma unroll
    for (int nb = 0; nb < NB; ++nb) {
        int g = sm.w.nid[nb];
        if (g < 0) continue;
        int i = g & (NN - 1);
        if (i == 0) {
            P.c_root[(g >> 16) * MD + t] = cv[nb];
        } else {
            float f = sigmoidf_(af[nb] + b_f + P.E_fx[(size_t)sm.w.ptok[nb] * MD + t]);
            int p = sm.w.par[nb];
            atomicAdd(&P.h_sum[(size_t)p * MD + t], sm.w.hls[nb][t]);
            atomicAdd(&P.fc_sum[(size_t)p * MD + t], f * cv[nb]);
        }
    }
    if (fence) __threadfence();   // deep path: make atomics visible before next depth
}

// ---------- init ancestor/depth ----------
__global__ void init_anc_kernel(Params P) {
    int stride = gridDim.x * blockDim.x;
    for (int g = blockIdx.x * blockDim.x + threadIdx.x; g < TWO_N; g += stride) {
        int tree = g >> 16, i = g & (NN - 1);
        if (i == 0) { P.anc_a[g] = g; P.dep_a[g] = 0; }
        else {
            const int* par = tree ? P.r_parent : P.l_parent;
            P.anc_a[g] = (tree << 16) | par[i];
            P.dep_a[g] = 1;
        }
    }
}

// ---------- E tables: E_ioux = emb_W@Wioux + bioux ; E_fx = emb_W@Wfx + bfx ----------
__global__ void etab_kernel(Params P) {
    __shared__ SMem sm;
    int t = threadIdx.x;
    for (int v0 = blockIdx.x * 4; v0 < VOCAB; v0 += gridDim.x * 4) {
        __syncthreads();
        #pragma unroll
        for (int r = 0; r < 4; ++r)
            sm.e.es[r][t] = (v0 + r < VOCAB) ? P.emb_W[(size_t)(v0 + r) * MD + t] : 0.f;
        __syncthreads();
        float a0[4] = {0.f,0.f,0.f,0.f}, a1[4] = {0.f,0.f,0.f,0.f};
        float a2[4] = {0.f,0.f,0.f,0.f}, a3[4] = {0.f,0.f,0.f,0.f};
        for (int k = 0; k < MD; ++k) {
            float wi = P.Wioux[k * G3 + t];
            float wo = P.Wioux[k * G3 + 256 + t];
            float wu = P.Wioux[k * G3 + 512 + t];
            float wf = P.Wfx[k * MD + t];
            #pragma unroll
            for (int r = 0; r < 4; ++r) {
                float e = sm.e.es[r][k];
                a0[r] += wi * e; a1[r] += wo * e; a2[r] += wu * e; a3[r] += wf * e;
            }
        }
        float bi = P.bioux[t], bo = P.bioux[256 + t], bu = P.bioux[512 + t], bf = P.bfx[t];
        for (int r = 0; r < 4; ++r) {
            if (v0 + r < VOCAB) {
                P.E_ioux[(size_t)(v0 + r) * G3 + t]       = a0[r] + bi;
                P.E_ioux[(size_t)(v0 + r) * G3 + 256 + t] = a1[r] + bo;
                P.E_ioux[(size_t)(v0 + r) * G3 + 512 + t] = a2[r] + bu;
                P.E_fx[(size_t)(v0 + r) * MD + t]         = a3[r] + bf;
            }
        }
        __syncthreads();
    }
}

// ---------- pointer doubling step ----------
__global__ void jump_kernel(const int* __restrict__ pa, const int* __restrict__ pd,
                            int* __restrict__ qa, int* __restrict__ qd) {
    int stride = gridDim.x * blockDim.x;
    for (int g = blockIdx.x * blockDim.x + threadIdx.x; g < TWO_N; g += stride) {
        int a = pa[g];
        qd[g] = pd[g] + pd[a];
        qa[g] = pa[a];
    }
}

__global__ void hist_kernel(Params P) {
    int stride = gridDim.x * blockDim.x;
    for (int g = blockIdx.x * blockDim.x + threadIdx.x; g < TWO_N; g += stride) {
        int tree = g >> 16;
        int d = P.dep_a[g];
        atomicAdd(&P.cnt[tree * DMAX + d], 1);
        atomicMax(&P.maxd[tree], d);
    }
}

__global__ void prefix_kernel(Params P) {
    if (threadIdx.x == 0 && blockIdx.x == 0) {
        for (int tree = 0; tree < 2; ++tree) {
            int run = tree * NN;                 // tree 1's segment starts at NN
            int md = P.maxd[tree];
            for (int d = 0; d <= md; ++d) {
                P.offs[tree * DMAX + d] = run;
                run += P.cnt[tree * DMAX + d];
            }
        }
    }
}

__global__ void scatter_kernel(Params P) {
    int stride = gridDim.x * blockDim.x;
    for (int g = blockIdx.x * blockDim.x + threadIdx.x; g < TWO_N; g += stride) {
        int tree = g >> 16;
        int d = P.dep_a[g];
        int pos = atomicAdd(&P.cur[tree * DMAX + d], 1);
        P.order[P.offs[tree * DMAX + d] + pos] = g;
    }
}

// ---------- deep tail (depths >= DFIX), single block, sequential ----------
__global__ __launch_bounds__(NT, 2) void deep_kernel(Params P, int tree) {
    __shared__ SMem sm;
    int t = threadIdx.x;
    int md = P.maxd[tree];
    for (int d = md; d >= DFIX; --d) {
        int nwave = P.cnt[tree * DMAX + d];
        int start = P.offs[tree * DMAX + d];
        int ngroups = (nwave + NB - 1) / NB;
        for (int grp = 0; grp < ngroups; ++grp) {
            int base = grp * NB;
            int cntv = nwave - base; if (cntv > NB) cntv = NB;
            process_group(P, sm, start + base, cntv, t, true);
        }
        __syncthreads();
    }
}

// ---------- one depth wave ----------
__global__ __launch_bounds__(NT, 2) void wave_kernel(Params P, int tree, int d) {
    __shared__ SMem sm;
    int t = threadIdx.x;
    int nwave = P.cnt[tree * DMAX + d];
    if (nwave == 0) return;
    int start = P.offs[tree * DMAX + d];
    int ngroups = (nwave + NB - 1) / NB;
    for (int grp = blockIdx.x; grp < ngroups; grp += gridDim.x) {
        int base = grp * NB;
        int cntv = nwave - base; if (cntv > NB) cntv = NB;
        process_group(P, sm, start + base, cntv, t, false);
    }
}

// ---------- similarity head ----------
__global__ void head_kernel(Params P) {
    __shared__ SMem sm;
    int t = threadIdx.x;
    float cl = P.c_root[t], cr = P.c_root[MD + t];
    sm.h.vec[t] = cl * cr;
    sm.h.vec[MD + t] = fabsf(cl - cr);
    __syncthreads();
    float acc = 0.f;
    for (int j = 0; j < 2 * MD; ++j) acc += sm.h.vec[j] * P.Wh[(size_t)j * MD + t];
    float hid = sigmoidf_(acc + P.bh[t]);
    sm.h.red[0][t] = hid * P.Wp[t * 2 + 0];
    sm.h.red[1][t] = hid * P.Wp[t * 2 + 1];
    __syncthreads();
    for (int s = 128; s > 0; s >>= 1) {
        if (t < s) {
            sm.h.red[0][t] += sm.h.red[0][t + s];
            sm.h.red[1][t] += sm.h.red[1][t + s];
        }
        __syncthreads();
    }
    if (t == 0) {
        float l0 = sm.h.red[0][0] + P.bp[0];
        float l1 = sm.h.red[1][0] + P.bp[1];
        float mx = fmaxf(l0, l1);
        float e0 = __expf(l0 - mx), e1 = __expf(l1 - mx);
        float inv = 1.0f / (e0 + e1);
        P.out[0] = e0 * inv;
        P.out[1] = e1 * inv;
    }
}

extern "C" void kernel_launch(void* const* d_in, const int* in_sizes, int n_in,
                              void* d_out, int out_size, void* d_ws, size_t ws_size,
                              hipStream_t stream) {
    Params P;
    P.l_tokens = (const int*)d_in[0];
    P.l_parent = (const int*)d_in[1];
    P.r_tokens = (const int*)d_in[2];
    P.r_parent = (const int*)d_in[3];
    P.emb_W = (const float*)d_in[4];
    P.Wioux = (const float*)d_in[5];
    P.bioux = (const float*)d_in[6];
    P.Wiouh = (const float*)d_in[7];
    P.biouh = (const float*)d_in[8];
    P.Wfx   = (const float*)d_in[9];
    P.bfx   = (const float*)d_in[10];
    P.Wfh   = (const float*)d_in[11];
    P.bfh   = (const float*)d_in[12];
    P.Wh    = (const float*)d_in[13];
    P.bh    = (const float*)d_in[14];
    P.Wp    = (const float*)d_in[15];
    P.bp    = (const float*)d_in[16];
    P.out   = (float*)d_out;

    char* w = (char*)d_ws;
    auto alloc = [&](size_t bytes) {
        char* r = w;
        w += (bytes + 255) & ~(size_t)255;
        return r;
    };
    // total ~142 MB (state arrays are per-tree, reused sequentially)
    P.E_ioux = (float*)alloc((size_t)VOCAB * G3 * 4);
    P.E_fx   = (float*)alloc((size_t)VOCAB * MD * 4);
    P.h_sum  = (float*)alloc((size_t)NN * MD * 4);
    P.fc_sum = (float*)alloc((size_t)NN * MD * 4);
    P.c_root = (float*)alloc(2 * MD * 4);
    P.anc_a  = (int*)alloc((size_t)TWO_N * 4);
    P.anc_b  = (int*)alloc((size_t)TWO_N * 4);
    P.dep_a  = (int*)alloc((size_t)TWO_N * 4);
    P.dep_b  = (int*)alloc((size_t)TWO_N * 4);
    P.cnt    = (int*)alloc((size_t)2 * DMAX * 4);
    P.offs   = (int*)alloc((size_t)2 * DMAX * 4);
    P.cur    = (int*)alloc((size_t)2 * DMAX * 4);
    P.order  = (int*)alloc((size_t)TWO_N * 4);
    P.maxd   = (int*)alloc(256);

    // zero-init
    hipMemsetAsync(P.cnt,  0, (size_t)2 * DMAX * 4, stream);
    hipMemsetAsync(P.cur,  0, (size_t)2 * DMAX * 4, stream);
    hipMemsetAsync(P.maxd, 0, 8, stream);

    init_anc_kernel<<<256, NT, 0, stream>>>(P);
    etab_kernel<<<250, NT, 0, stream>>>(P);

    // pointer doubling: 16 iters covers depth up to 65536
    int* pa = P.anc_a; int* pd = P.dep_a; int* qa = P.anc_b; int* qd = P.dep_b;
    for (int it = 0; it < 16; ++it) {
        jump_kernel<<<256, NT, 0, stream>>>(pa, pd, qa, qd);
        int* tmp = pa; pa = qa; qa = tmp;
        tmp = pd; pd = qd; qd = tmp;
    }
    // after 16 swaps depth is back in dep_a

    hist_kernel<<<256, NT, 0, stream>>>(P);
    prefix_kernel<<<1, 64, 0, stream>>>(P);
    scatter_kernel<<<256, NT, 0, stream>>>(P);

    for (int tree = 0; tree < 2; ++tree) {
        hipMemsetAsync(P.h_sum,  0, (size_t)NN * MD * 4, stream);
        hipMemsetAsync(P.fc_sum, 0, (size_t)NN * MD * 4, stream);
        deep_kernel<<<1, NT, 0, stream>>>(P, tree);
        for (int d = DFIX - 1; d >= 0; --d) {
            wave_kernel<<<512, NT, 0, stream>>>(P, tree, d);
        }
    }
    head_kernel<<<1, NT, 0, stream>>>(P);
}

// Round 4
// 7149.885 us; speedup vs baseline: 1.1118x; 1.1118x over previous
//
#include <hip/hip_runtime.h>
#include <math.h>

#define NN 65536
#define TWO_N (2 * NN)
#define VOCAB 1000
#define MD 256
#define G3 768
#define DMAX 65536
#define DCAP 128
#define NB 16
#define NT 256
#define DFIX 48

struct Params {
    const int* l_tokens; const int* l_parent;
    const int* r_tokens; const int* r_parent;
    const float* emb_W;
    const float* Wioux; const float* bioux;
    const float* Wiouh; const float* biouh;
    const float* Wfx;   const float* bfx;
    const float* Wfh;   const float* bfh;
    const float* Wh;    const float* bh;
    const float* Wp;    const float* bp;
    float* out;
    // workspace
    float* E_ioux;   // [VOCAB][768]  (includes bioux)
    float* E_fx;     // [VOCAB][256]  (includes bfx)
    float* h_sum;    // [NN][256]  (one tree at a time)
    float* fc_sum;   // [NN][256]
    float* c_root;   // [2][256]
    int* anc_a; int* anc_b; int* dep_a; int* dep_b;  // [2N]
    int* cnt; int* offs; int* cur;                    // [2*DMAX] (tree-major)
    int* order;                                        // [2N] (tree 0 nodes first)
    int* maxd;                                         // [2]
};

union SMem {
    struct { float es[4][MD]; } e;
    struct {
        float hls[NB][MD];
        int nid[NB]; int loc[NB]; int tok[NB]; int par[NB]; int ptok[NB];
    } w;
    struct { float vec[2 * MD]; float red[2][NT]; } h;
};

__device__ __forceinline__ float sigmoidf_(float x) {
    return 1.0f / (1.0f + __expf(-x));
}
__device__ __forceinline__ float tanhf_(float x) {
    float ex = __expf(2.0f * x);
    return 1.0f - 2.0f / (ex + 1.0f);
}

// processes NB nodes of ONE tree; state arrays are local-indexed [NN][256]
__device__ void process_group(const Params& P, SMem& sm, int base, int cntv,
                              int t, bool fence) {
    __syncthreads();   // protect smem reuse from previous group
    if (t < NB) {
        int g = -1, loc = 0, tok = 0, par = 0, ptok = 0;
        if (t < cntv) {
            g = P.order[base + t];
            int tree = g >> 16, i = g & (NN - 1);
            const int* toks = tree ? P.r_tokens : P.l_tokens;
            const int* pars = tree ? P.r_parent : P.l_parent;
            loc = i;
            tok = toks[i];
            int pl = pars[i];
            par = pl;
            ptok = toks[pl];
        }
        sm.w.nid[t] = g; sm.w.loc[t] = loc; sm.w.tok[t] = tok;
        sm.w.par[t] = par; sm.w.ptok[t] = ptok;
    }
    __syncthreads();
    #pragma unroll
    for (int nb = 0; nb < NB; ++nb) {
        int g = sm.w.nid[nb];
        sm.w.hls[nb][t] = (g >= 0) ? P.h_sum[(size_t)sm.w.loc[nb] * MD + t] : 0.0f;
    }
    __syncthreads();

    // ---- iou = E_ioux[tok] + h_sum @ Wiouh + biouh ; thread t owns element t ----
    float ai[NB], ao[NB], au[NB];
    #pragma unroll
    for (int nb = 0; nb < NB; ++nb) { ai[nb] = 0.f; ao[nb] = 0.f; au[nb] = 0.f; }
    const float* W = P.Wiouh;
    for (int k = 0; k < MD; k += 4) {
        float wi0 = W[(k + 0) * G3 + t];
        float wi1 = W[(k + 1) * G3 + t];
        float wi2 = W[(k + 2) * G3 + t];
        float wi3 = W[(k + 3) * G3 + t];
        float wo0 = W[(k + 0) * G3 + 256 + t];
        float wo1 = W[(k + 1) * G3 + 256 + t];
        float wo2 = W[(k + 2) * G3 + 256 + t];
        float wo3 = W[(k + 3) * G3 + 256 + t];
        float wu0 = W[(k + 0) * G3 + 512 + t];
        float wu1 = W[(k + 1) * G3 + 512 + t];
        float wu2 = W[(k + 2) * G3 + 512 + t];
        float wu3 = W[(k + 3) * G3 + 512 + t];
        #pragma unroll
        for (int nb = 0; nb < NB; ++nb) {
            float4 hv = *(const float4*)&sm.w.hls[nb][k];
            ai[nb] += wi0 * hv.x; ai[nb] += wi1 * hv.y; ai[nb] += wi2 * hv.z; ai[nb] += wi3 * hv.w;
            ao[nb] += wo0 * hv.x; ao[nb] += wo1 * hv.y; ao[nb] += wo2 * hv.z; ao[nb] += wo3 * hv.w;
            au[nb] += wu0 * hv.x; au[nb] += wu1 * hv.y; au[nb] += wu2 * hv.z; au[nb] += wu3 * hv.w;
        }
    }

    // ---- gates, c, h ----
    float cv[NB];
    float b_i = P.biouh[t], b_o = P.biouh[256 + t], b_u = P.biouh[512 + t];
    __syncthreads();   // all threads done reading h_sum rows in hls
    #pragma unroll
    for (int nb = 0; nb < NB; ++nb) {
        int g = sm.w.nid[nb];
        float hval = 0.0f, cval = 0.0f;
        if (g >= 0) {
            const float* Ei = P.E_ioux + (size_t)sm.w.tok[nb] * G3;
            float ig = Ei[t] + ai[nb] + b_i;
            float og = Ei[256 + t] + ao[nb] + b_o;
            float ug = Ei[512 + t] + au[nb] + b_u;
            cval = sigmoidf_(ig) * tanhf_(ug) + P.fc_sum[(size_t)sm.w.loc[nb] * MD + t];
            hval = sigmoidf_(og) * tanhf_(cval);
        }
        cv[nb] = cval;
        sm.w.hls[nb][t] = hval;   // overwrite with h
    }
    __syncthreads();

    // ---- f = sigmoid(h @ Wfh + bfh + E_fx[ptok]) ; scatter to parent ----
    float af[NB];
    #pragma unroll
    for (int nb = 0; nb < NB; ++nb) af[nb] = 0.f;
    const float* Wf = P.Wfh;
    for (int k = 0; k < MD; k += 4) {
        float wf0 = Wf[(k + 0) * MD + t];
        float wf1 = Wf[(k + 1) * MD + t];
        float wf2 = Wf[(k + 2) * MD + t];
        float wf3 = Wf[(k + 3) * MD + t];
        #pragma unroll
        for (int nb = 0; nb < NB; ++nb) {
            float4 hv = *(const float4*)&sm.w.hls[nb][k];
            af[nb] += wf0 * hv.x; af[nb] += wf1 * hv.y; af[nb] += wf2 * hv.z; af[nb] += wf3 * hv.w;
        }
    }
    float b_f = P.bfh[t];
    #pragma unroll
    for (int nb = 0; nb < NB; ++nb) {
        int g = sm.w.nid[nb];
        if (g < 0) continue;
        int i = g & (NN - 1);
        if (i == 0) {
            P.c_root[(g >> 16) * MD + t] = cv[nb];
        } else {
            float f = sigmoidf_(af[nb] + b_f + P.E_fx[(size_t)sm.w.ptok[nb] * MD + t]);
            int p = sm.w.par[nb];
            atomicAdd(&P.h_sum[(size_t)p * MD + t], sm.w.hls[nb][t]);
            atomicAdd(&P.fc_sum[(size_t)p * MD + t], f * cv[nb]);
        }
    }
    if (fence) __threadfence();   // deep path: make atomics visible before next depth
}

// ---------- init ancestor/depth ----------
__global__ void init_anc_kernel(Params P) {
    int stride = gridDim.x * blockDim.x;
    for (int g = blockIdx.x * blockDim.x + threadIdx.x; g < TWO_N; g += stride) {
        int tree = g >> 16, i = g & (NN - 1);
        if (i == 0) { P.anc_a[g] = g; P.dep_a[g] = 0; }
        else {
            const int* par = tree ? P.r_parent : P.l_parent;
            P.anc_a[g] = (tree << 16) | par[i];
            P.dep_a[g] = 1;
        }
    }
}

// ---------- E tables: E_ioux = emb_W@Wioux + bioux ; E_fx = emb_W@Wfx + bfx ----------
__global__ void etab_kernel(Params P) {
    __shared__ SMem sm;
    int t = threadIdx.x;
    for (int v0 = blockIdx.x * 4; v0 < VOCAB; v0 += gridDim.x * 4) {
        __syncthreads();
        #pragma unroll
        for (int r = 0; r < 4; ++r)
            sm.e.es[r][t] = (v0 + r < VOCAB) ? P.emb_W[(size_t)(v0 + r) * MD + t] : 0.f;
        __syncthreads();
        float a0[4] = {0.f,0.f,0.f,0.f}, a1[4] = {0.f,0.f,0.f,0.f};
        float a2[4] = {0.f,0.f,0.f,0.f}, a3[4] = {0.f,0.f,0.f,0.f};
        for (int k = 0; k < MD; ++k) {
            float wi = P.Wioux[k * G3 + t];
            float wo = P.Wioux[k * G3 + 256 + t];
            float wu = P.Wioux[k * G3 + 512 + t];
            float wf = P.Wfx[k * MD + t];
            #pragma unroll
            for (int r = 0; r < 4; ++r) {
                float e = sm.e.es[r][k];
                a0[r] += wi * e; a1[r] += wo * e; a2[r] += wu * e; a3[r] += wf * e;
            }
        }
        float bi = P.bioux[t], bo = P.bioux[256 + t], bu = P.bioux[512 + t], bf = P.bfx[t];
        for (int r = 0; r < 4; ++r) {
            if (v0 + r < VOCAB) {
                P.E_ioux[(size_t)(v0 + r) * G3 + t]       = a0[r] + bi;
                P.E_ioux[(size_t)(v0 + r) * G3 + 256 + t] = a1[r] + bo;
                P.E_ioux[(size_t)(v0 + r) * G3 + 512 + t] = a2[r] + bu;
                P.E_fx[(size_t)(v0 + r) * MD + t]         = a3[r] + bf;
            }
        }
        __syncthreads();
    }
}

// ---------- pointer doubling step ----------
__global__ void jump_kernel(const int* __restrict__ pa, const int* __restrict__ pd,
                            int* __restrict__ qa, int* __restrict__ qd) {
    int stride = gridDim.x * blockDim.x;
    for (int g = blockIdx.x * blockDim.x + threadIdx.x; g < TWO_N; g += stride) {
        int a = pa[g];
        qd[g] = pd[g] + pd[a];
        qa[g] = pa[a];
    }
}

// ---------- histogram: per-block LDS pre-reduction (kills same-address global atomics) ----------
__global__ void hist_kernel(Params P) {
    __shared__ int hcnt[2 * DCAP];
    __shared__ int hmax[2];
    int t = threadIdx.x;
    for (int i = t; i < 2 * DCAP; i += NT) hcnt[i] = 0;
    if (t < 2) hmax[t] = 0;
    __syncthreads();
    int stride = gridDim.x * blockDim.x;
    for (int g = blockIdx.x * blockDim.x + t; g < TWO_N; g += stride) {
        int tree = g >> 16;
        int d = P.dep_a[g];
        if (d < DCAP) {
            atomicAdd(&hcnt[tree * DCAP + d], 1);
            atomicMax(&hmax[tree], d);
        } else {   // pathological depth: rare/never — direct global
            atomicAdd(&P.cnt[tree * DMAX + d], 1);
            atomicMax(&P.maxd[tree], d);
        }
    }
    __syncthreads();
    for (int i = t; i < 2 * DCAP; i += NT) {
        int c = hcnt[i];
        if (c > 0) atomicAdd(&P.cnt[(i >= DCAP ? DMAX : 0) + (i & (DCAP - 1))], c);
    }
    if (t < 2) atomicMax(&P.maxd[t], hmax[t]);
}

__global__ void prefix_kernel(Params P) {
    if (threadIdx.x == 0 && blockIdx.x == 0) {
        for (int tree = 0; tree < 2; ++tree) {
            int run = tree * NN;                 // tree 1's segment starts at NN
            int md = P.maxd[tree];
            for (int d = 0; d <= md; ++d) {
                P.offs[tree * DMAX + d] = run;
                run += P.cnt[tree * DMAX + d];
            }
        }
    }
}

// ---------- scatter: block-level range reservation + LDS placement ----------
__global__ void scatter_kernel(Params P) {
    __shared__ int hcnt[2 * DCAP];
    __shared__ int hbase[2 * DCAP];
    int t = threadIdx.x;
    for (int i = t; i < 2 * DCAP; i += NT) hcnt[i] = 0;
    __syncthreads();
    int stride = gridDim.x * blockDim.x;
    // pass 1: count this block's depths
    for (int g = blockIdx.x * blockDim.x + t; g < TWO_N; g += stride) {
        int tree = g >> 16;
        int d = P.dep_a[g];
        if (d < DCAP) atomicAdd(&hcnt[tree * DCAP + d], 1);
    }
    __syncthreads();
    // reserve one contiguous range per non-empty bucket (ONE global atomic each)
    for (int i = t; i < 2 * DCAP; i += NT) {
        int c = hcnt[i];
        if (c > 0) {
            int idx = (i >= DCAP ? DMAX : 0) + (i & (DCAP - 1));
            hbase[i] = P.offs[idx] + atomicAdd(&P.cur[idx], c);
        }
        hcnt[i] = 0;   // reuse as running position within the reservation
    }
    __syncthreads();
    // pass 2: place
    for (int g = blockIdx.x * blockDim.x + t; g < TWO_N; g += stride) {
        int tree = g >> 16;
        int d = P.dep_a[g];
        if (d < DCAP) {
            int b = tree * DCAP + d;
            int pos = atomicAdd(&hcnt[b], 1);   // LDS atomic — fast
            P.order[hbase[b] + pos] = g;
        } else {
            int idx = tree * DMAX + d;
            int pos = atomicAdd(&P.cur[idx], 1);
            P.order[P.offs[idx] + pos] = g;
        }
    }
}

// ---------- deep tail (depths >= DFIX), single block, sequential ----------
__global__ __launch_bounds__(NT, 2) void deep_kernel(Params P, int tree) {
    __shared__ SMem sm;
    int t = threadIdx.x;
    int md = P.maxd[tree];
    for (int d = md; d >= DFIX; --d) {
        int nwave = P.cnt[tree * DMAX + d];
        int start = P.offs[tree * DMAX + d];
        int ngroups = (nwave + NB - 1) / NB;
        for (int grp = 0; grp < ngroups; ++grp) {
            int base = grp * NB;
            int cntv = nwave - base; if (cntv > NB) cntv = NB;
            process_group(P, sm, start + base, cntv, t, true);
        }
        __syncthreads();
    }
}

// ---------- one depth wave ----------
__global__ __launch_bounds__(NT, 2) void wave_kernel(Params P, int tree, int d) {
    __shared__ SMem sm;
    int t = threadIdx.x;
    int nwave = P.cnt[tree * DMAX + d];
    if (nwave == 0) return;
    int start = P.offs[tree * DMAX + d];
    int ngroups = (nwave + NB - 1) / NB;
    for (int grp = blockIdx.x; grp < ngroups; grp += gridDim.x) {
        int base = grp * NB;
        int cntv = nwave - base; if (cntv > NB) cntv = NB;
        process_group(P, sm, start + base, cntv, t, false);
    }
}

// ---------- similarity head ----------
__global__ void head_kernel(Params P) {
    __shared__ SMem sm;
    int t = threadIdx.x;
    float cl = P.c_root[t], cr = P.c_root[MD + t];
    sm.h.vec[t] = cl * cr;
    sm.h.vec[MD + t] = fabsf(cl - cr);
    __syncthreads();
    float acc = 0.f;
    for (int j = 0; j < 2 * MD; ++j) acc += sm.h.vec[j] * P.Wh[(size_t)j * MD + t];
    float hid = sigmoidf_(acc + P.bh[t]);
    sm.h.red[0][t] = hid * P.Wp[t * 2 + 0];
    sm.h.red[1][t] = hid * P.Wp[t * 2 + 1];
    __syncthreads();
    for (int s = 128; s > 0; s >>= 1) {
        if (t < s) {
            sm.h.red[0][t] += sm.h.red[0][t + s];
            sm.h.red[1][t] += sm.h.red[1][t + s];
        }
        __syncthreads();
    }
    if (t == 0) {
        float l0 = sm.h.red[0][0] + P.bp[0];
        float l1 = sm.h.red[1][0] + P.bp[1];
        float mx = fmaxf(l0, l1);
        float e0 = __expf(l0 - mx), e1 = __expf(l1 - mx);
        float inv = 1.0f / (e0 + e1);
        P.out[0] = e0 * inv;
        P.out[1] = e1 * inv;
    }
}

extern "C" void kernel_launch(void* const* d_in, const int* in_sizes, int n_in,
                              void* d_out, int out_size, void* d_ws, size_t ws_size,
                              hipStream_t stream) {
    Params P;
    P.l_tokens = (const int*)d_in[0];
    P.l_parent = (const int*)d_in[1];
    P.r_tokens = (const int*)d_in[2];
    P.r_parent = (const int*)d_in[3];
    P.emb_W = (const float*)d_in[4];
    P.Wioux = (const float*)d_in[5];
    P.bioux = (const float*)d_in[6];
    P.Wiouh = (const float*)d_in[7];
    P.biouh = (const float*)d_in[8];
    P.Wfx   = (const float*)d_in[9];
    P.bfx   = (const float*)d_in[10];
    P.Wfh   = (const float*)d_in[11];
    P.bfh   = (const float*)d_in[12];
    P.Wh    = (const float*)d_in[13];
    P.bh    = (const float*)d_in[14];
    P.Wp    = (const float*)d_in[15];
    P.bp    = (const float*)d_in[16];
    P.out   = (float*)d_out;

    char* w = (char*)d_ws;
    auto alloc = [&](size_t bytes) {
        char* r = w;
        w += (bytes + 255) & ~(size_t)255;
        return r;
    };
    // total ~142 MB (state arrays are per-tree, reused sequentially)
    P.E_ioux = (float*)alloc((size_t)VOCAB * G3 * 4);
    P.E_fx   = (float*)alloc((size_t)VOCAB * MD * 4);
    P.h_sum  = (float*)alloc((size_t)NN * MD * 4);
    P.fc_sum = (float*)alloc((size_t)NN * MD * 4);
    P.c_root = (float*)alloc(2 * MD * 4);
    P.anc_a  = (int*)alloc((size_t)TWO_N * 4);
    P.anc_b  = (int*)alloc((size_t)TWO_N * 4);
    P.dep_a  = (int*)alloc((size_t)TWO_N * 4);
    P.dep_b  = (int*)alloc((size_t)TWO_N * 4);
    P.cnt    = (int*)alloc((size_t)2 * DMAX * 4);
    P.offs   = (int*)alloc((size_t)2 * DMAX * 4);
    P.cur    = (int*)alloc((size_t)2 * DMAX * 4);
    P.order  = (int*)alloc((size_t)TWO_N * 4);
    P.maxd   = (int*)alloc(256);

    // zero-init
    hipMemsetAsync(P.cnt,  0, (size_t)2 * DMAX * 4, stream);
    hipMemsetAsync(P.cur,  0, (size_t)2 * DMAX * 4, stream);
    hipMemsetAsync(P.maxd, 0, 8, stream);

    init_anc_kernel<<<256, NT, 0, stream>>>(P);
    etab_kernel<<<250, NT, 0, stream>>>(P);

    // pointer doubling: 16 iters covers depth up to 65536
    int* pa = P.anc_a; int* pd = P.dep_a; int* qa = P.anc_b; int* qd = P.dep_b;
    for (int it = 0; it < 16; ++it) {
        jump_kernel<<<256, NT, 0, stream>>>(pa, pd, qa, qd);
        int* tmp = pa; pa = qa; qa = tmp;
        tmp = pd; pd = qd; qd = tmp;
    }
    // after 16 swaps depth is back in dep_a

    hist_kernel<<<64, NT, 0, stream>>>(P);
    prefix_kernel<<<1, 64, 0, stream>>>(P);
    scatter_kernel<<<64, NT, 0, stream>>>(P);

    for (int tree = 0; tree < 2; ++tree) {
        hipMemsetAsync(P.h_sum,  0, (size_t)NN * MD * 4, stream);
        hipMemsetAsync(P.fc_sum, 0, (size_t)NN * MD * 4, stream);
        deep_kernel<<<1, NT, 0, stream>>>(P, tree);
        for (int d = DFIX - 1; d >= 0; --d) {
            wave_kernel<<<256, NT, 0, stream>>>(P, tree, d);
        }
    }
    head_kernel<<<1, NT, 0, stream>>>(P);
}